// Round 9
// baseline (676.183 us; speedup 1.0000x reference)
//
#include <hip/hip_runtime.h>
#include <hip/hip_bf16.h>
#include <math.h>

#define N_NODES 100000
#define N_EDGES 500000
#define M0 8.0f
#define INV_SQRT32 0.17677669529663687f

#define NB_PROJ 1563   // ceil(100000/64)
#define NB_EE   3907   // ceil(500000/128)  (each ee block also hists its 128 edges)
#define GRID_MEGA (NB_PROJ + NB_EE)

typedef __attribute__((ext_vector_type(8))) short bf16x8;
typedef __attribute__((ext_vector_type(4))) float f32x4;

static __device__ __forceinline__ unsigned short f2bf(float f) {
    __hip_bfloat16 h = __float2bfloat16(f);
    return *(unsigned short*)&h;
}

static __device__ __forceinline__ void split4(float4 v, ushort4& hv, ushort4& lv) {
    const unsigned short h0 = f2bf(v.x), h1 = f2bf(v.y),
                         h2 = f2bf(v.z), h3 = f2bf(v.w);
    hv.x = h0; hv.y = h1; hv.z = h2; hv.w = h3;
    lv.x = f2bf(v.x - __uint_as_float((unsigned)h0 << 16));
    lv.y = f2bf(v.y - __uint_as_float((unsigned)h1 << 16));
    lv.z = f2bf(v.z - __uint_as_float((unsigned)h2 << 16));
    lv.w = f2bf(v.w - __uint_as_float((unsigned)h3 << 16));
}

// ---------------------------------------------------------------------------
// prep: split weights into bf16 hi/lo (Markidis) AND zero the cursor array.
// ---------------------------------------------------------------------------
__global__ __launch_bounds__(256) void prep_kernel(
    const float* __restrict__ Wq, const float* __restrict__ Wk,
    const float* __restrict__ Wv, const float* __restrict__ Ws,
    const float* __restrict__ We,
    unsigned short* __restrict__ WBh, unsigned short* __restrict__ WBl,
    unsigned short* __restrict__ WEh, unsigned short* __restrict__ WEl,
    int* __restrict__ cursor)
{
    const int i = blockIdx.x * 256 + threadIdx.x;
    if (i < N_NODES) cursor[i] = 0;
    if (i < 65536) {
        const int p = i >> 14;
        const float* W = (p == 0) ? Wq : (p == 1) ? Wk : (p == 2) ? Wv : Ws;
        const float v = W[i & 16383];
        const unsigned short h = f2bf(v);
        WBh[i] = h;
        WBl[i] = f2bf(v - __uint_as_float((unsigned)h << 16));
    } else if (i < 73728) {
        const int idx = i - 65536;
        const float v = We[idx];
        const unsigned short h = f2bf(v);
        WEh[idx] = h;
        WEl[idx] = f2bf(v - __uint_as_float((unsigned)h << 16));
    }
}

// ---------------------------------------------------------------------------
// mega: node-proj MFMA + edge-embed MFMA (ee blocks also hist their edges).
// W fragments are WAVE-PRIVATE (wave reads only rows wid*16+fr) -> load
// B-fragments DIRECTLY from global into registers (one aligned 16-B load
// per lane, same addresses/volume as R7's DMA -> L2-absorbed, FETCH proven
// 92 MB). Removes the entire W LDS round-trip and all per-phase barriers.
// One __syncthreads per block. LDS 64 KB -> 32 KB.
// ---------------------------------------------------------------------------
__global__ __launch_bounds__(512, 4) void mega_kernel(
    const float* __restrict__ x, const int* __restrict__ ei,
    const float* __restrict__ ea,
    const unsigned short* __restrict__ WBh, const unsigned short* __restrict__ WBl,
    const unsigned short* __restrict__ WEh, const unsigned short* __restrict__ WEl,
    const float* __restrict__ bq, const float* __restrict__ bk,
    const float* __restrict__ bv, const float* __restrict__ bs,
    float* __restrict__ Qn, float* __restrict__ Kn, float* __restrict__ Vn,
    float* __restrict__ out, unsigned short* __restrict__ Ee,
    int* __restrict__ cursor)
{
    __shared__ __align__(16) unsigned short sAh[8192];
    __shared__ __align__(16) unsigned short sAl[8192];

    const int t = threadIdx.x;
    const int bid = blockIdx.x;

    const int lane = t & 63;
    const int wid = t >> 6;          // 0..7
    const int fr = lane & 15;
    const int fq = lane >> 4;

    if (bid < NB_PROJ) {
        // ---- node projection: 64 rows x (Q,K,V,S); wave owns 16 ch ----
        const long r0 = (long)bid * 64;

        for (int i = t; i < 2048; i += 512) {
            const int r = i >> 5;
            const int k4 = (i & 31) * 4;
            const long row = r0 + r;
            float4 v = (row < N_NODES) ? *(const float4*)&x[row * 128 + k4]
                                       : make_float4(0.f, 0.f, 0.f, 0.f);
            ushort4 hv, lv; split4(v, hv, lv);
            const int di = r * 128 + (k4 ^ ((r & 7) << 3));
            *(ushort4*)&sAh[di] = hv;
            *(ushort4*)&sAl[di] = lv;
        }
        __syncthreads();   // the ONLY barrier: x tile visible

        for (int p = 0; p < 4; ++p) {
            const float* bias = (p == 0) ? bq : (p == 1) ? bk : (p == 2) ? bv : bs;
            float* dst        = (p == 0) ? Qn : (p == 1) ? Kn : (p == 2) ? Vn : out;

            // wave's private W row = channel wid*16+fr
            const unsigned short* Wh = WBh + p * 16384 + (wid * 16 + fr) * 128;
            const unsigned short* Wl = WBl + p * 16384 + (wid * 16 + fr) * 128;

            f32x4 acc[4];
#pragma unroll
            for (int m = 0; m < 4; ++m) acc[m] = (f32x4){0.f, 0.f, 0.f, 0.f};

#pragma unroll
            for (int kc = 0; kc < 2; ++kc) {
#pragma unroll
                for (int ks = 0; ks < 2; ++ks) {
                    const int kx = kc * 64 + ks * 32 + fq * 8;
                    // B-fragment straight from global (L2-hot, 16 B/lane)
                    const bf16x8 wh = *(const bf16x8*)&Wh[kx];
                    const bf16x8 wl = *(const bf16x8*)&Wl[kx];
                    bf16x8 ah[4], al[4];
#pragma unroll
                    for (int m = 0; m < 4; ++m) {
                        const int r = m * 16 + fr;
                        const int di = r * 128 + (kx ^ ((r & 7) << 3));
                        ah[m] = *(const bf16x8*)&sAh[di];
                        al[m] = *(const bf16x8*)&sAl[di];
                    }
#pragma unroll
                    for (int m = 0; m < 4; ++m) {
                        acc[m] = __builtin_amdgcn_mfma_f32_16x16x32_bf16(
                            ah[m], wh, acc[m], 0, 0, 0);
                        acc[m] = __builtin_amdgcn_mfma_f32_16x16x32_bf16(
                            ah[m], wl, acc[m], 0, 0, 0);
                        acc[m] = __builtin_amdgcn_mfma_f32_16x16x32_bf16(
                            al[m], wh, acc[m], 0, 0, 0);
                    }
                }
            }

            const float bb = bias[wid * 16 + fr];
#pragma unroll
            for (int m = 0; m < 4; ++m) {
                const long rowb = r0 + m * 16 + fq * 4;
#pragma unroll
                for (int j = 0; j < 4; ++j) {
                    if (rowb + j < N_NODES)
                        dst[(rowb + j) * 128 + wid * 16 + fr] = acc[m][j] + bb;
                }
            }
        }
    } else {
        // ---- edge embedding GEMM (+ own-tile histogram) ----
        const long e0 = (long)(bid - NB_PROJ) * 128;
        const int wr = wid >> 2;     // 0..1: edge rows wr*64
        const int wc = wid & 3;      // 0..3: ch cols wc*32

        if (t < 128) {
            const long e = e0 + t;
            if (e < N_EDGES) atomicAdd(&cursor[ei[N_EDGES + e]], 1);
        }

        for (int i = t; i < 2048; i += 512) {
            const int r = i >> 4;
            const int k4 = (i & 15) * 4;
            const long e = e0 + r;
            float4 v = (e < N_EDGES) ? *(const float4*)&ea[e * 64 + k4]
                                     : make_float4(0.f, 0.f, 0.f, 0.f);
            ushort4 hv, lv; split4(v, hv, lv);
            const int di = r * 64 + (k4 ^ ((r & 7) << 3));
            *(ushort4*)&sAh[di] = hv;
            *(ushort4*)&sAl[di] = lv;
        }
        __syncthreads();

        f32x4 acc[4][2];
#pragma unroll
        for (int m = 0; m < 4; ++m)
#pragma unroll
            for (int n = 0; n < 2; ++n) acc[m][n] = (f32x4){0.f, 0.f, 0.f, 0.f};

#pragma unroll
        for (int ks = 0; ks < 2; ++ks) {
            const int kk = ks * 32 + fq * 8;
            bf16x8 ah[4], al[4], wh[2], wl[2];
#pragma unroll
            for (int m = 0; m < 4; ++m) {
                const int r = wr * 64 + m * 16 + fr;
                const int di = r * 64 + (kk ^ ((r & 7) << 3));
                ah[m] = *(const bf16x8*)&sAh[di];
                al[m] = *(const bf16x8*)&sAl[di];
            }
#pragma unroll
            for (int n = 0; n < 2; ++n) {
                const int gi = (wc * 32 + n * 16 + fr) * 64 + kk;
                wh[n] = *(const bf16x8*)&WEh[gi];
                wl[n] = *(const bf16x8*)&WEl[gi];
            }
#pragma unroll
            for (int m = 0; m < 4; ++m)
#pragma unroll
                for (int n = 0; n < 2; ++n) {
                    acc[m][n] = __builtin_amdgcn_mfma_f32_16x16x32_bf16(
                        ah[m], wh[n], acc[m][n], 0, 0, 0);
                    acc[m][n] = __builtin_amdgcn_mfma_f32_16x16x32_bf16(
                        ah[m], wl[n], acc[m][n], 0, 0, 0);
                    acc[m][n] = __builtin_amdgcn_mfma_f32_16x16x32_bf16(
                        al[m], wh[n], acc[m][n], 0, 0, 0);
                }
        }

#pragma unroll
        for (int m = 0; m < 4; ++m) {
            const long e = e0 + wr * 64 + m * 16 + fq * 4;
#pragma unroll
            for (int j = 0; j < 4; ++j) {
                if (e + j < N_EDGES) {
#pragma unroll
                    for (int n = 0; n < 2; ++n)
                        Ee[(e + j) * 128 + wc * 32 + n * 16 + fr] =
                            f2bf(acc[m][n][j]);
                }
            }
        }
    }
}

// ---------------------------------------------------------------------------
// CSR scan: single block, 1024 threads.
// ---------------------------------------------------------------------------
__global__ __launch_bounds__(1024) void csr_scan_kernel(
    int* __restrict__ cursor, int* __restrict__ csr_off)
{
    __shared__ int wsum[16];
    const int t = threadIdx.x;
    const int lane = t & 63;
    const int wid = t >> 6;
    const int n0 = t * 100;
    const bool active = (t < 1000);

    int tsum = 0;
    if (active) {
        for (int q = 0; q < 25; ++q) {
            const int4 d = *(const int4*)&cursor[n0 + q * 4];
            tsum += d.x + d.y + d.z + d.w;
        }
    }
    int inc = tsum;
#pragma unroll
    for (int o = 1; o < 64; o <<= 1) {
        const int v = __shfl_up(inc, o, 64);
        if (lane >= o) inc += v;
    }
    if (lane == 63) wsum[wid] = inc;
    __syncthreads();
    if (t == 0) {
        int run = 0;
#pragma unroll
        for (int w = 0; w < 16; ++w) { const int v = wsum[w]; wsum[w] = run; run += v; }
        csr_off[N_NODES] = run;
    }
    __syncthreads();
    if (active) {
        int run = wsum[wid] + inc - tsum;
        for (int q = 0; q < 25; ++q) {
            const int n = n0 + q * 4;
            const int4 d = *(const int4*)&cursor[n];
            int4 offv;
            offv.x = run; run += d.x;
            offv.y = run; run += d.y;
            offv.z = run; run += d.z;
            offv.w = run; run += d.w;
            *(int4*)&csr_off[n] = offv;
            *(int4*)&cursor[n]  = offv;
        }
    }
}

// ---------------------------------------------------------------------------
// CSR fill: one packed int2 {eid, src} store per edge.
// ---------------------------------------------------------------------------
__global__ __launch_bounds__(256) void csr_fill_kernel(
    const int* __restrict__ ei, int* __restrict__ cursor,
    int2* __restrict__ csr_es)
{
    const int e = blockIdx.x * 256 + threadIdx.x;
    if (e >= N_EDGES) return;
    const int dst = ei[N_EDGES + e];
    const int pos = atomicAdd(&cursor[dst], 1);
    csr_es[pos] = make_int2(e, ei[e]);
}

// ---------------------------------------------------------------------------
// Fused attention: single pass, serial edge broadcast (verified-best access
// pattern), j-loop unrolled x2: both edges' loads issue back-to-back and
// both shfl-reduce chains interleave -> 2x memory-level parallelism with
// unchanged coalescing. Accumulation order identical (a then b).
// ---------------------------------------------------------------------------
__global__ __launch_bounds__(256) void fused_attn_kernel(
    const int* __restrict__ csr_off, const int2* __restrict__ csr_es,
    const unsigned short* __restrict__ Ee,
    const float* __restrict__ Qn, const float* __restrict__ Kn,
    const float* __restrict__ Vn, float* __restrict__ out)
{
    const int lane = threadIdx.x & 63;
    const int l2 = lane * 2;
    const long n = (long)blockIdx.x * 4 + (threadIdx.x >> 6);

    const int off0 = csr_off[n];
    const int off1 = csr_off[n + 1];
    const float2 q = *(const float2*)&Qn[n * 128 + l2];

    float dsum = 0.f;
    float2 acc = make_float2(0.f, 0.f);
    for (int base = off0; base < off1; base += 64) {
        const int cnt = min(64, off1 - base);
        int2 es = make_int2(0, 0);
        if (base + lane < off1) es = csr_es[base + lane];
        for (int j = 0; j < cnt; j += 2) {
            const int j1 = (j + 1 < cnt) ? j + 1 : j;
            const long eA = __shfl(es.x, j, 64);
            const long sA = __shfl(es.y, j, 64);
            const long eB = __shfl(es.x, j1, 64);
            const long sB = __shfl(es.y, j1, 64);
            const unsigned ua = *(const unsigned*)&Ee[eA * 128 + l2];
            const float2 ka = *(const float2*)&Kn[sA * 128 + l2];
            const float2 va = *(const float2*)&Vn[sA * 128 + l2];
            const unsigned ub = *(const unsigned*)&Ee[eB * 128 + l2];
            const float2 kb = *(const float2*)&Kn[sB * 128 + l2];
            const float2 vb = *(const float2*)&Vn[sB * 128 + l2];
            const float a0 = __uint_as_float(ua << 16);
            const float a1 = __uint_as_float(ua & 0xffff0000u);
            const float b0 = __uint_as_float(ub << 16);
            const float b1 = __uint_as_float(ub & 0xffff0000u);
            float pa = q.x * (ka.x + a0) + q.y * (ka.y + a1);
            float pb = q.x * (kb.x + b0) + q.y * (kb.y + b1);
#pragma unroll
            for (int o = 1; o < 16; o <<= 1) {
                pa += __shfl_xor(pa, o, 64);
                pb += __shfl_xor(pb, o, 64);
            }
            const float ana = __expf(pa * INV_SQRT32 - M0);
            dsum += ana;
            acc.x = fmaf(va.x + a0, ana, acc.x);
            acc.y = fmaf(va.y + a1, ana, acc.y);
            if (j + 1 < cnt) {
                const float anb = __expf(pb * INV_SQRT32 - M0);
                dsum += anb;
                acc.x = fmaf(vb.x + b0, anb, acc.x);
                acc.y = fmaf(vb.y + b1, anb, acc.y);
            }
        }
    }
    const float rd = 1.f / (dsum + 1e-16f);
    float2 o = *(const float2*)&out[n * 128 + l2];
    o.x = fmaf(acc.x, rd, o.x);
    o.y = fmaf(acc.y, rd, o.y);
    *(float2*)&out[n * 128 + l2] = o;
}

// ---------------------------------------------------------------------------
// Workspace layout (float offsets unless noted):
//   Qn      [N,128]   @ 0
//   Kn      [N,128]   @ 12,800,000
//   Vn      [N,128]   @ 25,600,000
//   csr_off [N+1]     @ 38,400,000  (int)
//   cursor  [N]       @ 38,500,004  (int)
//   csr_es  [E] int2  @ 38,600,004  (byte 154,400,016, 8B-aligned)
//   WBh     [65536]us @ 40,000,000
//   WBl     [65536]us @ 40,050,000
//   WEh     [8192]us  @ 40,100,000
//   WEl     [8192]us  @ 40,110,000
//   Ee bf16 [E,128]   @ byte 163,200,032
// ---------------------------------------------------------------------------
extern "C" void kernel_launch(void* const* d_in, const int* in_sizes, int n_in,
                              void* d_out, int out_size, void* d_ws, size_t ws_size,
                              hipStream_t stream)
{
    const float* x  = (const float*)d_in[0];
    const int*   ei = (const int*)d_in[1];
    const float* ea = (const float*)d_in[2];
    const float* Wq = (const float*)d_in[3];
    const float* bq = (const float*)d_in[4];
    const float* Wk = (const float*)d_in[5];
    const float* bk = (const float*)d_in[6];
    const float* Wv = (const float*)d_in[7];
    const float* bv = (const float*)d_in[8];
    const float* We = (const float*)d_in[9];
    const float* Ws = (const float*)d_in[10];
    const float* bs = (const float*)d_in[11];
    float* out = (float*)d_out;

    float* ws = (float*)d_ws;
    float* Qn = ws;
    float* Kn = ws + 12800000;
    float* Vn = ws + 25600000;
    int* csr_off = (int*)(ws + 38400000);
    int* cursor  = (int*)(ws + 38500004);
    int2* csr_es = (int2*)(ws + 38600004);
    unsigned short* WBh = (unsigned short*)(ws + 40000000);
    unsigned short* WBl = (unsigned short*)(ws + 40050000);
    unsigned short* WEh = (unsigned short*)(ws + 40100000);
    unsigned short* WEl = (unsigned short*)(ws + 40110000);
    unsigned short* Ee = (unsigned short*)((char*)d_ws + 163200032);

    prep_kernel<<<391, 256, 0, stream>>>(Wq, Wk, Wv, Ws, We,
                                         WBh, WBl, WEh, WEl, cursor);

    mega_kernel<<<GRID_MEGA, 512, 0, stream>>>(x, ei, ea,
                                               WBh, WBl, WEh, WEl,
                                               bq, bk, bv, bs,
                                               Qn, Kn, Vn, out, Ee, cursor);

    csr_scan_kernel<<<1, 1024, 0, stream>>>(cursor, csr_off);

    csr_fill_kernel<<<(N_EDGES + 255) / 256, 256, 0, stream>>>(ei, cursor, csr_es);

    fused_attn_kernel<<<25000, 256, 0, stream>>>(csr_off, csr_es, Ee,
                                                 Qn, Kn, Vn, out);
}

// Round 10
// 544.413 us; speedup vs baseline: 1.2420x; 1.2420x over previous
//
#include <hip/hip_runtime.h>
#include <hip/hip_bf16.h>
#include <math.h>

#define N_NODES 100000
#define N_EDGES 500000
#define M0 8.0f
#define INV_SQRT32 0.17677669529663687f

#define NB_PROJ 1563   // ceil(100000/64)
#define NB_EE   3907   // ceil(500000/128)  (each ee block also hists its 128 edges)
#define GRID_MEGA (NB_PROJ + NB_EE)

typedef __attribute__((ext_vector_type(8))) short bf16x8;
typedef __attribute__((ext_vector_type(4))) float f32x4;

static __device__ __forceinline__ unsigned short f2bf(float f) {
    __hip_bfloat16 h = __float2bfloat16(f);
    return *(unsigned short*)&h;
}

static __device__ __forceinline__ void split4(float4 v, ushort4& hv, ushort4& lv) {
    const unsigned short h0 = f2bf(v.x), h1 = f2bf(v.y),
                         h2 = f2bf(v.z), h3 = f2bf(v.w);
    hv.x = h0; hv.y = h1; hv.z = h2; hv.w = h3;
    lv.x = f2bf(v.x - __uint_as_float((unsigned)h0 << 16));
    lv.y = f2bf(v.y - __uint_as_float((unsigned)h1 << 16));
    lv.z = f2bf(v.z - __uint_as_float((unsigned)h2 << 16));
    lv.w = f2bf(v.w - __uint_as_float((unsigned)h3 << 16));
}

// direct global->LDS DMA, 16 B per lane
static __device__ __forceinline__ void gl_lds16(
    const unsigned short* __restrict__ g, unsigned short* l)
{
    __builtin_amdgcn_global_load_lds(
        (const __attribute__((address_space(1))) unsigned int*)g,
        (__attribute__((address_space(3))) unsigned int*)l, 16, 0, 0);
}

// ---------------------------------------------------------------------------
// prep: split weights into bf16 hi/lo (Markidis) AND zero the cursor array.
// ---------------------------------------------------------------------------
__global__ __launch_bounds__(256) void prep_kernel(
    const float* __restrict__ Wq, const float* __restrict__ Wk,
    const float* __restrict__ Wv, const float* __restrict__ Ws,
    const float* __restrict__ We,
    unsigned short* __restrict__ WBh, unsigned short* __restrict__ WBl,
    unsigned short* __restrict__ WEh, unsigned short* __restrict__ WEl,
    int* __restrict__ cursor)
{
    const int i = blockIdx.x * 256 + threadIdx.x;
    if (i < N_NODES) cursor[i] = 0;
    if (i < 65536) {
        const int p = i >> 14;
        const float* W = (p == 0) ? Wq : (p == 1) ? Wk : (p == 2) ? Wv : Ws;
        const float v = W[i & 16383];
        const unsigned short h = f2bf(v);
        WBh[i] = h;
        WBl[i] = f2bf(v - __uint_as_float((unsigned)h << 16));
    } else if (i < 73728) {
        const int idx = i - 65536;
        const float v = We[idx];
        const unsigned short h = f2bf(v);
        WEh[idx] = h;
        WEl[idx] = f2bf(v - __uint_as_float((unsigned)h << 16));
    }
}

// ---------------------------------------------------------------------------
// mega: node-proj MFMA + edge-embed MFMA (ee blocks also hist their edges).
// R7-verified structure: W staged through LDS via global_load_lds width=16
// with pre-swizzled source + linear dest (TWICE-confirmed law: shared
// weights must be LDS-staged once per block; per-lane global re-reads
// thrash L2 — R4, R9). K and V projections now stored BF16 (write traffic
// 340->289 MB; attn gather -40%).
// ---------------------------------------------------------------------------
__global__ __launch_bounds__(512, 4) void mega_kernel(
    const float* __restrict__ x, const int* __restrict__ ei,
    const float* __restrict__ ea,
    const unsigned short* __restrict__ WBh, const unsigned short* __restrict__ WBl,
    const unsigned short* __restrict__ WEh, const unsigned short* __restrict__ WEl,
    const float* __restrict__ bq, const float* __restrict__ bk,
    const float* __restrict__ bv, const float* __restrict__ bs,
    float* __restrict__ Qn, unsigned short* __restrict__ Kbf,
    unsigned short* __restrict__ Vbf,
    float* __restrict__ out, unsigned short* __restrict__ Ee,
    int* __restrict__ cursor)
{
    __shared__ __align__(16) unsigned short sAh[8192];
    __shared__ __align__(16) unsigned short sAl[8192];
    __shared__ __align__(16) unsigned short sWh[8192];
    __shared__ __align__(16) unsigned short sWl[8192];

    const int t = threadIdx.x;
    const int bid = blockIdx.x;

    const int lane = t & 63;
    const int wid = t >> 6;          // 0..7
    const int fr = lane & 15;
    const int fq = lane >> 4;

    if (bid < NB_PROJ) {
        // ---- node projection: 64 rows x (Q,K,V,S); wave owns 16 ch ----
        const long r0 = (long)bid * 64;

        for (int i = t; i < 2048; i += 512) {
            const int r = i >> 5;
            const int k4 = (i & 31) * 4;
            const long row = r0 + r;
            float4 v = (row < N_NODES) ? *(const float4*)&x[row * 128 + k4]
                                       : make_float4(0.f, 0.f, 0.f, 0.f);
            ushort4 hv, lv; split4(v, hv, lv);
            const int di = r * 128 + (k4 ^ ((r & 7) << 3));
            *(ushort4*)&sAh[di] = hv;
            *(ushort4*)&sAl[di] = lv;
        }

        for (int p = 0; p < 4; ++p) {
            const float* bias = (p == 0) ? bq : (p == 1) ? bk : (p == 2) ? bv : bs;

            f32x4 acc[4];
#pragma unroll
            for (int m = 0; m < 4; ++m) acc[m] = (f32x4){0.f, 0.f, 0.f, 0.f};

            for (int kc = 0; kc < 2; ++kc) {
                __syncthreads();   // prev phase's LDS reads done
                // W chunk [128 ch][64 k] hi/lo via LDS-DMA, pre-swz source
#pragma unroll
                for (int c = 0; c < 2; ++c) {
                    const int i = c * 512 + t;
                    const int r = i >> 3;
                    const int d = i & 7;
                    const int gi = p * 16384 + r * 128 + kc * 64 + ((d ^ (r & 7)) * 8);
                    gl_lds16(&WBh[gi], &sWh[i * 8]);
                    gl_lds16(&WBl[gi], &sWl[i * 8]);
                }
                __syncthreads();   // drains vmcnt -> LDS contents valid

#pragma unroll
                for (int ks = 0; ks < 2; ++ks) {
                    const int kx = kc * 64 + ks * 32 + fq * 8;
                    const int kw = ks * 32 + fq * 8;
                    bf16x8 ah[4], al[4], wh, wl;
#pragma unroll
                    for (int m = 0; m < 4; ++m) {
                        const int r = m * 16 + fr;
                        const int di = r * 128 + (kx ^ ((r & 7) << 3));
                        ah[m] = *(const bf16x8*)&sAh[di];
                        al[m] = *(const bf16x8*)&sAl[di];
                    }
                    {
                        const int r = wid * 16 + fr;
                        const int di = r * 64 + (kw ^ ((r & 7) << 3));
                        wh = *(const bf16x8*)&sWh[di];
                        wl = *(const bf16x8*)&sWl[di];
                    }
#pragma unroll
                    for (int m = 0; m < 4; ++m) {
                        acc[m] = __builtin_amdgcn_mfma_f32_16x16x32_bf16(
                            ah[m], wh, acc[m], 0, 0, 0);
                        acc[m] = __builtin_amdgcn_mfma_f32_16x16x32_bf16(
                            ah[m], wl, acc[m], 0, 0, 0);
                        acc[m] = __builtin_amdgcn_mfma_f32_16x16x32_bf16(
                            al[m], wh, acc[m], 0, 0, 0);
                    }
                }
            }

            const float bb = bias[wid * 16 + fr];
            if (p == 1 || p == 2) {
                unsigned short* dstb = (p == 1) ? Kbf : Vbf;
#pragma unroll
                for (int m = 0; m < 4; ++m) {
                    const long rowb = r0 + m * 16 + fq * 4;
#pragma unroll
                    for (int j = 0; j < 4; ++j) {
                        if (rowb + j < N_NODES)
                            dstb[(rowb + j) * 128 + wid * 16 + fr] =
                                f2bf(acc[m][j] + bb);
                    }
                }
            } else {
                float* dst = (p == 0) ? Qn : out;
#pragma unroll
                for (int m = 0; m < 4; ++m) {
                    const long rowb = r0 + m * 16 + fq * 4;
#pragma unroll
                    for (int j = 0; j < 4; ++j) {
                        if (rowb + j < N_NODES)
                            dst[(rowb + j) * 128 + wid * 16 + fr] = acc[m][j] + bb;
                    }
                }
            }
        }
    } else {
        // ---- edge embedding GEMM (+ own-tile histogram) ----
        const long e0 = (long)(bid - NB_PROJ) * 128;
        const int wr = wid >> 2;     // 0..1: edge rows wr*64
        const int wc = wid & 3;      // 0..3: ch cols wc*32

        if (t < 128) {
            const long e = e0 + t;
            if (e < N_EDGES) atomicAdd(&cursor[ei[N_EDGES + e]], 1);
        }

        // We [128 ch][64 k] hi/lo via LDS-DMA, pre-swz source
#pragma unroll
        for (int c = 0; c < 2; ++c) {
            const int i = c * 512 + t;
            const int r = i >> 3;
            const int d = i & 7;
            const int gi = r * 64 + ((d ^ (r & 7)) * 8);
            gl_lds16(&WEh[gi], &sWh[i * 8]);
            gl_lds16(&WEl[gi], &sWl[i * 8]);
        }
        // ea tile [128][64] -> hi/lo (VALU split; can't DMA)
        for (int i = t; i < 2048; i += 512) {
            const int r = i >> 4;
            const int k4 = (i & 15) * 4;
            const long e = e0 + r;
            float4 v = (e < N_EDGES) ? *(const float4*)&ea[e * 64 + k4]
                                     : make_float4(0.f, 0.f, 0.f, 0.f);
            ushort4 hv, lv; split4(v, hv, lv);
            const int di = r * 64 + (k4 ^ ((r & 7) << 3));
            *(ushort4*)&sAh[di] = hv;
            *(ushort4*)&sAl[di] = lv;
        }
        __syncthreads();

        f32x4 acc[4][2];
#pragma unroll
        for (int m = 0; m < 4; ++m)
#pragma unroll
            for (int n = 0; n < 2; ++n) acc[m][n] = (f32x4){0.f, 0.f, 0.f, 0.f};

#pragma unroll
        for (int ks = 0; ks < 2; ++ks) {
            const int kk = ks * 32 + fq * 8;
            bf16x8 ah[4], al[4], wh[2], wl[2];
#pragma unroll
            for (int m = 0; m < 4; ++m) {
                const int r = wr * 64 + m * 16 + fr;
                const int di = r * 64 + (kk ^ ((r & 7) << 3));
                ah[m] = *(const bf16x8*)&sAh[di];
                al[m] = *(const bf16x8*)&sAl[di];
            }
#pragma unroll
            for (int n = 0; n < 2; ++n) {
                const int r = wc * 32 + n * 16 + fr;
                const int di = r * 64 + (kk ^ ((r & 7) << 3));
                wh[n] = *(const bf16x8*)&sWh[di];
                wl[n] = *(const bf16x8*)&sWl[di];
            }
#pragma unroll
            for (int m = 0; m < 4; ++m)
#pragma unroll
                for (int n = 0; n < 2; ++n) {
                    acc[m][n] = __builtin_amdgcn_mfma_f32_16x16x32_bf16(
                        ah[m], wh[n], acc[m][n], 0, 0, 0);
                    acc[m][n] = __builtin_amdgcn_mfma_f32_16x16x32_bf16(
                        ah[m], wl[n], acc[m][n], 0, 0, 0);
                    acc[m][n] = __builtin_amdgcn_mfma_f32_16x16x32_bf16(
                        al[m], wh[n], acc[m][n], 0, 0, 0);
                }
        }

#pragma unroll
        for (int m = 0; m < 4; ++m) {
            const long e = e0 + wr * 64 + m * 16 + fq * 4;
#pragma unroll
            for (int j = 0; j < 4; ++j) {
                if (e + j < N_EDGES) {
#pragma unroll
                    for (int n = 0; n < 2; ++n)
                        Ee[(e + j) * 128 + wc * 32 + n * 16 + fr] =
                            f2bf(acc[m][n][j]);
                }
            }
        }
    }
}

// ---------------------------------------------------------------------------
// CSR scan: single block, 1024 threads.
// ---------------------------------------------------------------------------
__global__ __launch_bounds__(1024) void csr_scan_kernel(
    int* __restrict__ cursor, int* __restrict__ csr_off)
{
    __shared__ int wsum[16];
    const int t = threadIdx.x;
    const int lane = t & 63;
    const int wid = t >> 6;
    const int n0 = t * 100;
    const bool active = (t < 1000);

    int tsum = 0;
    if (active) {
        for (int q = 0; q < 25; ++q) {
            const int4 d = *(const int4*)&cursor[n0 + q * 4];
            tsum += d.x + d.y + d.z + d.w;
        }
    }
    int inc = tsum;
#pragma unroll
    for (int o = 1; o < 64; o <<= 1) {
        const int v = __shfl_up(inc, o, 64);
        if (lane >= o) inc += v;
    }
    if (lane == 63) wsum[wid] = inc;
    __syncthreads();
    if (t == 0) {
        int run = 0;
#pragma unroll
        for (int w = 0; w < 16; ++w) { const int v = wsum[w]; wsum[w] = run; run += v; }
        csr_off[N_NODES] = run;
    }
    __syncthreads();
    if (active) {
        int run = wsum[wid] + inc - tsum;
        for (int q = 0; q < 25; ++q) {
            const int n = n0 + q * 4;
            const int4 d = *(const int4*)&cursor[n];
            int4 offv;
            offv.x = run; run += d.x;
            offv.y = run; run += d.y;
            offv.z = run; run += d.z;
            offv.w = run; run += d.w;
            *(int4*)&csr_off[n] = offv;
            *(int4*)&cursor[n]  = offv;
        }
    }
}

// ---------------------------------------------------------------------------
// CSR fill: one packed int2 {eid, src} store per edge.
// ---------------------------------------------------------------------------
__global__ __launch_bounds__(256) void csr_fill_kernel(
    const int* __restrict__ ei, int* __restrict__ cursor,
    int2* __restrict__ csr_es)
{
    const int e = blockIdx.x * 256 + threadIdx.x;
    if (e >= N_EDGES) return;
    const int dst = ei[N_EDGES + e];
    const int pos = atomicAdd(&cursor[dst], 1);
    csr_es[pos] = make_int2(e, ei[e]);
}

// ---------------------------------------------------------------------------
// Fused attention: single pass, serial edge broadcast (verified-best).
// K and V now gathered as bf16 (4 B/lane each, was 8 B) -> per-edge gather
// 1.28 KB -> 768 B. Plain loop (unroll x2 measured = 0, R9).
// ---------------------------------------------------------------------------
__global__ __launch_bounds__(256) void fused_attn_kernel(
    const int* __restrict__ csr_off, const int2* __restrict__ csr_es,
    const unsigned short* __restrict__ Ee,
    const float* __restrict__ Qn, const unsigned short* __restrict__ Kbf,
    const unsigned short* __restrict__ Vbf, float* __restrict__ out)
{
    const int lane = threadIdx.x & 63;
    const int l2 = lane * 2;
    const long n = (long)blockIdx.x * 4 + (threadIdx.x >> 6);

    const int off0 = csr_off[n];
    const int off1 = csr_off[n + 1];
    const float2 q = *(const float2*)&Qn[n * 128 + l2];

    float dsum = 0.f;
    float2 acc = make_float2(0.f, 0.f);
    for (int base = off0; base < off1; base += 64) {
        const int cnt = min(64, off1 - base);
        int2 es = make_int2(0, 0);
        if (base + lane < off1) es = csr_es[base + lane];
        for (int j = 0; j < cnt; ++j) {
            const long e = __shfl(es.x, j, 64);
            const long s = __shfl(es.y, j, 64);
            const unsigned ue = *(const unsigned*)&Ee[e * 128 + l2];
            const unsigned uk = *(const unsigned*)&Kbf[s * 128 + l2];
            const float ea0 = __uint_as_float(ue << 16);
            const float ea1 = __uint_as_float(ue & 0xffff0000u);
            const float k0 = __uint_as_float(uk << 16);
            const float k1 = __uint_as_float(uk & 0xffff0000u);
            float p = q.x * (k0 + ea0) + q.y * (k1 + ea1);
#pragma unroll
            for (int o = 1; o < 16; o <<= 1) p += __shfl_xor(p, o, 64);
            const float an = __expf(p * INV_SQRT32 - M0);
            dsum += an;
            const unsigned uv = *(const unsigned*)&Vbf[s * 128 + l2];
            const float v0 = __uint_as_float(uv << 16);
            const float v1 = __uint_as_float(uv & 0xffff0000u);
            acc.x = fmaf(v0 + ea0, an, acc.x);
            acc.y = fmaf(v1 + ea1, an, acc.y);
        }
    }
    const float rd = 1.f / (dsum + 1e-16f);
    float2 o = *(const float2*)&out[n * 128 + l2];
    o.x = fmaf(acc.x, rd, o.x);
    o.y = fmaf(acc.y, rd, o.y);
    *(float2*)&out[n * 128 + l2] = o;
}

// ---------------------------------------------------------------------------
// Workspace layout (float offsets unless noted):
//   Qn      [N,128]      @ 0
//   Kbf     [N,128] us   @ 12,800,000 (byte 51,200,000)
//   Vbf     [N,128] us   @ 25,600,000 (byte 102,400,000)
//   csr_off [N+1]        @ 38,400,000  (int)
//   cursor  [N]          @ 38,500,004  (int)
//   csr_es  [E] int2     @ 38,600,004  (byte 154,400,016, 8B-aligned)
//   WBh     [65536]us    @ 40,000,000
//   WBl     [65536]us    @ 40,050,000
//   WEh     [8192]us     @ 40,100,000
//   WEl     [8192]us     @ 40,110,000
//   Ee bf16 [E,128]      @ byte 163,200,032
// ---------------------------------------------------------------------------
extern "C" void kernel_launch(void* const* d_in, const int* in_sizes, int n_in,
                              void* d_out, int out_size, void* d_ws, size_t ws_size,
                              hipStream_t stream)
{
    const float* x  = (const float*)d_in[0];
    const int*   ei = (const int*)d_in[1];
    const float* ea = (const float*)d_in[2];
    const float* Wq = (const float*)d_in[3];
    const float* bq = (const float*)d_in[4];
    const float* Wk = (const float*)d_in[5];
    const float* bk = (const float*)d_in[6];
    const float* Wv = (const float*)d_in[7];
    const float* bv = (const float*)d_in[8];
    const float* We = (const float*)d_in[9];
    const float* Ws = (const float*)d_in[10];
    const float* bs = (const float*)d_in[11];
    float* out = (float*)d_out;

    float* ws = (float*)d_ws;
    float* Qn = ws;
    unsigned short* Kbf = (unsigned short*)(ws + 12800000);
    unsigned short* Vbf = (unsigned short*)(ws + 25600000);
    int* csr_off = (int*)(ws + 38400000);
    int* cursor  = (int*)(ws + 38500004);
    int2* csr_es = (int2*)(ws + 38600004);
    unsigned short* WBh = (unsigned short*)(ws + 40000000);
    unsigned short* WBl = (unsigned short*)(ws + 40050000);
    unsigned short* WEh = (unsigned short*)(ws + 40100000);
    unsigned short* WEl = (unsigned short*)(ws + 40110000);
    unsigned short* Ee = (unsigned short*)((char*)d_ws + 163200032);

    prep_kernel<<<391, 256, 0, stream>>>(Wq, Wk, Wv, Ws, We,
                                         WBh, WBl, WEh, WEl, cursor);

    mega_kernel<<<GRID_MEGA, 512, 0, stream>>>(x, ei, ea,
                                               WBh, WBl, WEh, WEl,
                                               bq, bk, bv, bs,
                                               Qn, Kbf, Vbf, out, Ee, cursor);

    csr_scan_kernel<<<1, 1024, 0, stream>>>(cursor, csr_off);

    csr_fill_kernel<<<(N_EDGES + 255) / 256, 256, 0, stream>>>(ei, cursor, csr_es);

    fused_attn_kernel<<<25000, 256, 0, stream>>>(csr_off, csr_es, Ee,
                                                 Qn, Kbf, Vbf, out);
}